// Round 1
// baseline (319.192 us; speedup 1.0000x reference)
//
#include <hip/hip_runtime.h>
#include <math.h>

// Problem constants
#define NQ 8192          // points per batch
#define BB 2             // batch
#define H_IN 384
#define W_IN 512
#define HH0 96           // conv out H
#define WW0 128          // conv out W
#define HH1 32           // pooled H
#define WW1 42           // pooled W

// ---------------------------------------------------------------------------
// Kernel 1: transpose conv weights (128,3,7,7) -> wT[tap][oc], tap=c*49+kh*7+kw
// ---------------------------------------------------------------------------
__global__ void transpose_w_kernel(const float* __restrict__ w, float* __restrict__ wT) {
    int idx = blockIdx.x * 256 + threadIdx.x;
    if (idx < 147 * 128) {
        int tap = idx >> 7;          // idx / 128
        int oc  = idx & 127;
        wT[idx] = w[oc * 147 + tap];
    }
}

// ---------------------------------------------------------------------------
// Kernel 2: conv 7x7 stride 4 pad 3 + bias + relu, channels-last output
// in: frames (4,3,384,512) normalized on the fly; out: (4,96,128,128) [bs,y,x,oc]
// block: 256 thr = 4 wave-groups; each wave: oc = lane (+64), 16 pixels
// grid: (2 ow-tiles, 96 oh, 4 bs)
// ---------------------------------------------------------------------------
__global__ __launch_bounds__(256) void conv_kernel(
    const float* __restrict__ frames, const float* __restrict__ wT,
    const float* __restrict__ bias, float* __restrict__ out)
{
    __shared__ float lds[3 * 7 * 260];    // patch [c][kh][col], stride 260
    const int bs  = blockIdx.z;
    const int oh  = blockIdx.y;
    const int ow0 = blockIdx.x * 64;
    const int tid = threadIdx.x;

    // stage input patch: rows oh*4-3+kh, cols ow0*4-3 + [0,258]
    for (int idx = tid; idx < 3 * 7 * 259; idx += 256) {
        int c   = idx / 1813;               // 7*259
        int rem = idx - c * 1813;
        int kh  = rem / 259;
        int col = rem - kh * 259;
        int gy  = oh * 4 - 3 + kh;
        int gx  = ow0 * 4 - 3 + col;
        float v = 0.0f;
        if (gy >= 0 && gy < H_IN && gx >= 0 && gx < W_IN) {
            float t = frames[((size_t)(bs * 3 + c) * H_IN + gy) * W_IN + gx];
            v = 2.0f * (t / 255.0f) - 1.0f;
        }
        lds[c * 1820 + kh * 260 + col] = v;
    }
    __syncthreads();

    const int oc = tid & 63;
    const int g  = tid >> 6;                // wave-uniform pixel group
    float a0[16], a1[16];
#pragma unroll
    for (int p = 0; p < 16; ++p) { a0[p] = 0.0f; a1[p] = 0.0f; }

#pragma unroll
    for (int c = 0; c < 3; ++c) {
#pragma unroll
        for (int kh = 0; kh < 7; ++kh) {
            const float* row = lds + c * 1820 + kh * 260 + g * 64;
            float w0[7], w1v[7];
#pragma unroll
            for (int kw = 0; kw < 7; ++kw) {
                int tap = (c * 7 + kh) * 7 + kw;
                w0[kw]  = wT[tap * 128 + oc];
                w1v[kw] = wT[tap * 128 + oc + 64];
            }
#pragma unroll
            for (int p = 0; p < 16; ++p) {
                const float4 A  = *(const float4*)(row + p * 4);
                const float4 Bv = *(const float4*)(row + p * 4 + 4);
                float s0 = a0[p], s1 = a1[p];
                s0 = fmaf(A.x,  w0[0], s0);  s1 = fmaf(A.x,  w1v[0], s1);
                s0 = fmaf(A.y,  w0[1], s0);  s1 = fmaf(A.y,  w1v[1], s1);
                s0 = fmaf(A.z,  w0[2], s0);  s1 = fmaf(A.z,  w1v[2], s1);
                s0 = fmaf(A.w,  w0[3], s0);  s1 = fmaf(A.w,  w1v[3], s1);
                s0 = fmaf(Bv.x, w0[4], s0);  s1 = fmaf(Bv.x, w1v[4], s1);
                s0 = fmaf(Bv.y, w0[5], s0);  s1 = fmaf(Bv.y, w1v[5], s1);
                s0 = fmaf(Bv.z, w0[6], s0);  s1 = fmaf(Bv.z, w1v[6], s1);
                a0[p] = s0; a1[p] = s1;
            }
        }
    }

    const float b0  = bias[oc];
    const float b1b = bias[oc + 64];
#pragma unroll
    for (int p = 0; p < 16; ++p) {
        int ow = ow0 + g * 16 + p;
        size_t ob = ((size_t)(bs * HH0 + oh) * WW0 + ow) * 128;
        out[ob + oc]      = fmaxf(a0[p] + b0, 0.0f);
        out[ob + oc + 64] = fmaxf(a1[p] + b1b, 0.0f);
    }
}

// ---------------------------------------------------------------------------
// Kernel 3: 3x3/s3 avg pool, channels-last (4,96,128,128) -> (4,32,42,128)
// ---------------------------------------------------------------------------
__global__ void pool_kernel(const float* __restrict__ in, float* __restrict__ out) {
    int idx = blockIdx.x * 256 + threadIdx.x;          // 4*32*42*128 = 688128
    if (idx >= 4 * HH1 * WW1 * 128) return;
    int c = idx & 127;
    int r = idx >> 7;
    int px = r % WW1; r /= WW1;
    int py = r % HH1;
    int bs = r / HH1;
    float s = 0.0f;
#pragma unroll
    for (int dy = 0; dy < 3; ++dy)
#pragma unroll
        for (int dx = 0; dx < 3; ++dx)
            s += in[(((size_t)bs * HH0 + py * 3 + dy) * WW0 + px * 3 + dx) * 128 + c];
    out[idx] = s / 9.0f;
}

// ---------------------------------------------------------------------------
// Kernel 4: one tracking level. One wave per point (lane = channel, 2 ch/lane).
// ---------------------------------------------------------------------------
__global__ __launch_bounds__(256) void level_kernel(
    const float* __restrict__ fm, int hh, int ww,
    const float* __restrict__ cur_in,
    const float* __restrict__ w1, const float* __restrict__ b1,
    const float* __restrict__ wp, const float* __restrict__ bp,
    const float* __restrict__ wvw, const float* __restrict__ bvv,
    float* __restrict__ cur_out,
    const float* __restrict__ vis_in,
    float* __restrict__ vis_out,
    int is_last)
{
    __shared__ float smem[4 * 2480];
    const int tid  = threadIdx.x;
    const int wvi  = tid >> 6;
    const int lane = tid & 63;
    const int wid  = blockIdx.x * 4 + wvi;     // 0..16383
    const int b    = wid >> 13;
    const int n    = wid & (NQ - 1);

    float* fl   = smem + wvi * 2480;           // [9][132]
    float* ml   = fl + 1188;                   // [9][132]
    float* cl   = fl + 2376;                   // [81]
    float* invf = fl + 2457;                   // [9]
    float* invm = fl + 2466;                   // [9]

    const float px = cur_in[((size_t)b * NQ + n) * 2 + 0];
    const float py = cur_in[((size_t)b * NQ + n) * 2 + 1];

    const float wwm1 = (float)(ww - 1);
    const float hhm1 = (float)(hh - 1);
    const float gxb  = px * 2.0f - 1.0f;
    const float gyb  = py * 2.0f - 1.0f;

    const float* fb0 = fm + (size_t)(b * 2 + 0) * hh * ww * 128;
    const float* fb1 = fm + (size_t)(b * 2 + 1) * hh * ww * 128;

#pragma unroll
    for (int k = 0; k < 9; ++k) {
        const int kx = k % 3, ky = k / 3;
        const float offx = ((float)(kx - 1)) / wwm1 * 2.0f;
        const float offy = ((float)(ky - 1)) / hhm1 * 2.0f;
        const float gx = gxb + offx;
        const float gy = gyb + offy;
        const float ix = (gx + 1.0f) * 0.5f * wwm1;
        const float iy = (gy + 1.0f) * 0.5f * hhm1;
        const float x0f = floorf(ix), y0f = floorf(iy);
        const float x1f = x0f + 1.0f, y1f = y0f + 1.0f;
        const float wx1 = ix - x0f, wx0 = 1.0f - wx1;
        const float wy1 = iy - y0f, wy0 = 1.0f - wy1;
        const float vx0 = (x0f >= 0.0f && x0f <= wwm1) ? 1.0f : 0.0f;
        const float vx1 = (x1f >= 0.0f && x1f <= wwm1) ? 1.0f : 0.0f;
        const float vy0 = (y0f >= 0.0f && y0f <= hhm1) ? 1.0f : 0.0f;
        const float vy1 = (y1f >= 0.0f && y1f <= hhm1) ? 1.0f : 0.0f;
        const int xi0 = (int)fminf(fmaxf(x0f, 0.0f), wwm1);
        const int xi1 = (int)fminf(fmaxf(x1f, 0.0f), wwm1);
        const int yi0 = (int)fminf(fmaxf(y0f, 0.0f), hhm1);
        const int yi1 = (int)fminf(fmaxf(y1f, 0.0f), hhm1);
        const float wA = wx0 * wy0 * vx0 * vy0;
        const float wB = wx1 * wy0 * vx1 * vy0;
        const float wC = wx0 * wy1 * vx0 * vy1;
        const float wD = wx1 * wy1 * vx1 * vy1;
        const int oA = (yi0 * ww + xi0) * 128 + lane;
        const int oB = (yi0 * ww + xi1) * 128 + lane;
        const int oC = (yi1 * ww + xi0) * 128 + lane;
        const int oD = (yi1 * ww + xi1) * 128 + lane;

        float f0 = wA * fb0[oA] + wB * fb0[oB] + wC * fb0[oC] + wD * fb0[oD];
        float f1 = wA * fb0[oA + 64] + wB * fb0[oB + 64] + wC * fb0[oC + 64] + wD * fb0[oD + 64];
        fl[k * 132 + lane]      = f0;
        fl[k * 132 + lane + 64] = f1;
        float ss = f0 * f0 + f1 * f1;
#pragma unroll
        for (int m = 32; m >= 1; m >>= 1) ss += __shfl_xor(ss, m);
        if (lane == 0) invf[k] = 1.0f / fmaxf(sqrtf(ss), 1e-12f);

        float m0 = wA * fb1[oA] + wB * fb1[oB] + wC * fb1[oC] + wD * fb1[oD];
        float m1 = wA * fb1[oA + 64] + wB * fb1[oB + 64] + wC * fb1[oC + 64] + wD * fb1[oD + 64];
        ml[k * 132 + lane]      = m0;
        ml[k * 132 + lane + 64] = m1;
        float ss2 = m0 * m0 + m1 * m1;
#pragma unroll
        for (int m = 32; m >= 1; m >>= 1) ss2 += __shfl_xor(ss2, m);
        if (lane == 0) invm[k] = 1.0f / fmaxf(sqrtf(ss2), 1e-12f);
    }
    __syncthreads();

    // corr[h][k] = dot(f_h, m_k) * invf[h] * invm[k]; entries e = lane, lane+64
#pragma unroll
    for (int rep = 0; rep < 2; ++rep) {
        int e = lane + rep * 64;
        if (e < 81) {
            int h9 = e / 9, k9 = e % 9;
            const float* fr = fl + h9 * 132;
            const float* mr = ml + k9 * 132;
            float s = 0.0f;
#pragma unroll
            for (int c = 0; c < 128; c += 4) {
                float4 a  = *(const float4*)(fr + c);
                float4 bb = *(const float4*)(mr + c);
                s += a.x * bb.x; s += a.y * bb.y; s += a.z * bb.z; s += a.w * bb.w;
            }
            cl[e] = s * invf[h9] * invm[k9];
        }
    }
    __syncthreads();

    // MLP: h = relu(corr @ w1 + b1); lane holds outputs lane, lane+64, +128, +192
    float h0 = b1[lane], h1 = b1[lane + 64], h2 = b1[lane + 128], h3 = b1[lane + 192];
    for (int i = 0; i < 81; ++i) {
        const float cv = cl[i];
        const float* wr = w1 + i * 256;
        h0 = fmaf(cv, wr[lane], h0);
        h1 = fmaf(cv, wr[lane + 64], h1);
        h2 = fmaf(cv, wr[lane + 128], h2);
        h3 = fmaf(cv, wr[lane + 192], h3);
    }
    h0 = fmaxf(h0, 0.0f); h1 = fmaxf(h1, 0.0f);
    h2 = fmaxf(h2, 0.0f); h3 = fmaxf(h3, 0.0f);

    // pred logits + vis partials
    float pp[9];
#pragma unroll
    for (int j = 0; j < 9; ++j) pp[j] = 0.0f;
    float va = 0.0f;
    {
        const float* r = wp + lane * 9;
#pragma unroll
        for (int j = 0; j < 9; ++j) pp[j] = fmaf(h0, r[j], pp[j]);
        va = fmaf(h0, wvw[lane], va);
    }
    {
        const float* r = wp + (lane + 64) * 9;
#pragma unroll
        for (int j = 0; j < 9; ++j) pp[j] = fmaf(h1, r[j], pp[j]);
        va = fmaf(h1, wvw[lane + 64], va);
    }
    {
        const float* r = wp + (lane + 128) * 9;
#pragma unroll
        for (int j = 0; j < 9; ++j) pp[j] = fmaf(h2, r[j], pp[j]);
        va = fmaf(h2, wvw[lane + 128], va);
    }
    {
        const float* r = wp + (lane + 192) * 9;
#pragma unroll
        for (int j = 0; j < 9; ++j) pp[j] = fmaf(h3, r[j], pp[j]);
        va = fmaf(h3, wvw[lane + 192], va);
    }
#pragma unroll
    for (int j = 0; j < 9; ++j) {
        float v = pp[j];
#pragma unroll
        for (int m = 32; m >= 1; m >>= 1) v += __shfl_xor(v, m);
        pp[j] = v;
    }
#pragma unroll
    for (int m = 32; m >= 1; m >>= 1) va += __shfl_xor(va, m);

    // softmax(9), sigmoid, soft-argmax, update (all lanes redundantly)
    float lg[9];
#pragma unroll
    for (int j = 0; j < 9; ++j) lg[j] = pp[j] + bp[j];
    float mx = lg[0];
#pragma unroll
    for (int j = 1; j < 9; ++j) mx = fmaxf(mx, lg[j]);
    float ex[9]; float sum = 0.0f;
#pragma unroll
    for (int j = 0; j < 9; ++j) { ex[j] = expf(lg[j] - mx); sum += ex[j]; }
#pragma unroll
    for (int j = 0; j < 9; ++j) ex[j] = ex[j] / sum;

    float vis = 1.0f / (1.0f + expf(-(va + bvv[0])));

    const float ax = 1.0f / wwm1;   // R_WIN/(ww-1)
    const float ay = 1.0f / hhm1;
    float r0 = ex[0] + ex[1] + ex[2];
    float r1 = ex[3] + ex[4] + ex[5];
    float r2 = ex[6] + ex[7] + ex[8];
    float c0 = ex[0] + ex[3] + ex[6];
    float c1 = ex[1] + ex[4] + ex[7];
    float c2 = ex[2] + ex[5] + ex[8];
    float dx = r0 * (-ax) + r1 * 0.0f + r2 * ax;
    float dy = c0 * (-ay) + c1 * 0.0f + c2 * ay;
    float nx = px + dx, ny = py + dy;

    if (lane == 0) {
        size_t pi = (size_t)b * NQ + n;
        cur_out[pi * 2 + 0] = nx;
        cur_out[pi * 2 + 1] = ny;
        if (is_last) vis_out[pi] = (vis_in[pi] + vis) * 0.5f;
        else         vis_out[pi] = vis;
    }
}

// ---------------------------------------------------------------------------
extern "C" void kernel_launch(void* const* d_in, const int* in_sizes, int n_in,
                              void* d_out, int out_size, void* d_ws, size_t ws_size,
                              hipStream_t stream) {
    (void)in_sizes; (void)n_in; (void)out_size; (void)ws_size;
    const float* queries = (const float*)d_in[0];
    const float* frames  = (const float*)d_in[1];
    const float* conv_w  = (const float*)d_in[2];
    const float* conv_b  = (const float*)d_in[3];
    const float* w1      = (const float*)d_in[4];
    const float* b1      = (const float*)d_in[5];
    const float* wp      = (const float*)d_in[6];
    const float* bp      = (const float*)d_in[7];
    const float* wvw     = (const float*)d_in[8];
    const float* bvv     = (const float*)d_in[9];
    float* out = (float*)d_out;

    // workspace layout (floats): fm0 | fm1 | wT | cur_ws | vis_ws  (~28.2 MB)
    float* ws     = (float*)d_ws;
    float* fm0    = ws;                         // 4*96*128*128 = 6291456
    float* fm1    = fm0 + 6291456;              // 4*32*42*128  = 688128
    float* wT     = fm1 + 688128;               // 147*128      = 18816
    float* cur_ws = wT + 18816;                 // 2*8192*2     = 32768
    float* vis_ws = cur_ws + 32768;             // 2*8192       = 16384

    transpose_w_kernel<<<74, 256, 0, stream>>>(conv_w, wT);
    conv_kernel<<<dim3(2, HH0, 4), 256, 0, stream>>>(frames, wT, conv_b, fm0);
    pool_kernel<<<2688, 256, 0, stream>>>(fm0, fm1);
    // level 0: coarse (pooled) map, cur = queries
    level_kernel<<<4096, 256, 0, stream>>>(fm1, HH1, WW1, queries,
                                           w1, b1, wp, bp, wvw, bvv,
                                           cur_ws, nullptr, vis_ws, 0);
    // level 1: fine map, writes final outputs
    level_kernel<<<4096, 256, 0, stream>>>(fm0, HH0, WW0, cur_ws,
                                           w1, b1, wp, bp, wvw, bvv,
                                           out, vis_ws, out + 32768, 1);
}